// Round 5
// baseline (387.418 us; speedup 1.0000x reference)
//
#include <hip/hip_runtime.h>
#include <hip/hip_bf16.h>

#define BN   16
#define CN   16
#define HH   512
#define WW   512
#define CIN_ 10
#define HID_ 64
#define Y0_  100
#define X0_  100
#define OS_  300            // cropped output spatial size
#define OPIX (OS_ * OS_)    // 90000 pixels per (b,c) plane
#define QX_  (OS_ / 4)      // 75 quads per row
#define NQUAD (BN * OS_ * QX_)  // 360000 thread-work-items

typedef float vfloat4 __attribute__((ext_vector_type(4)));  // clang-native, ok for nontemporal builtins

// ---------------------------------------------------------------------------
// Kernel 1: tiny MLP -> theta (fp32 in / fp32 out).
// thread t = b*6 + j:  out[b][j] = sum_i (b0[i] + ty[b]·W0[i]) * W1[j,i] + b1[j]
// theta row0 = [1+0.1*o0, 0.1*o1, o2], row1 = [0.1*o3, 1+0.1*o4, o5]
// ---------------------------------------------------------------------------
__global__ void theta_kernel(const float* __restrict__ ty,
                             const float* __restrict__ W0,
                             const float* __restrict__ b0,
                             const float* __restrict__ W1,
                             const float* __restrict__ b1,
                             float* __restrict__ theta_ws,
                             float* __restrict__ theta_out)
{
    int t = threadIdx.x;
    if (t >= BN * 6) return;
    int b = t / 6;
    int j = t - b * 6;

    float tyv[CIN_];
#pragma unroll
    for (int k = 0; k < CIN_; ++k) tyv[k] = ty[b * CIN_ + k];

    float acc = b1[j];
#pragma unroll 4
    for (int i = 0; i < HID_; ++i) {
        float h = b0[i];
#pragma unroll
        for (int k = 0; k < CIN_; ++k) h += tyv[k] * W0[i * CIN_ + k];
        acc += h * W1[j * HID_ + i];
    }

    float v;
    if      (j == 0) v = 1.0f + 0.1f * acc;
    else if (j == 1) v = 0.1f * acc;
    else if (j == 2) v = acc;
    else if (j == 3) v = 0.1f * acc;
    else if (j == 4) v = 1.0f + 0.1f * acc;
    else             v = acc;

    theta_ws[t]  = v;
    theta_out[t] = v;
}

// ---------------------------------------------------------------------------
// Kernel 2: fused affine-grid + bilinear grid-sample + crop.
// 4 consecutive output-x pixels per thread ("quad"):
//   per +1 output x, ix steps by th0 and iy steps by th3 (affine), so one base
//   evaluation + 3 FMAs covers the quad. Indices/weights shared across all 16
//   channels; 16B nontemporal vector stores (aligned by construction).
// Zero-padding via per-tap weight zeroing; all-16-weights-zero fast path.
// ---------------------------------------------------------------------------
__global__ __launch_bounds__(256) void sample_kernel(
    const float* __restrict__ rmap,
    const float* __restrict__ theta,
    float* __restrict__ out)
{
    unsigned gid = blockIdx.x * 256u + threadIdx.x;
    if (gid >= (unsigned)NQUAD) return;

    unsigned b   = gid / (OS_ * QX_);
    unsigned rem = gid - b * (OS_ * QX_);
    unsigned yo  = rem / QX_;
    unsigned qx  = rem - yo * QX_;

    int x = (int)(qx * 4) + X0_;   // first pixel of the quad
    int y = (int)yo + Y0_;

    // normalized pixel-center coords: (2*p+1)/N - 1
    float xn = (float)(2 * x + 1) * (1.0f / WW) - 1.0f;
    float yn = (float)(2 * y + 1) * (1.0f / HH) - 1.0f;

    const float* th = theta + b * 6;
    float th0 = th[0], th1 = th[1], th2 = th[2];
    float th3 = th[3], th4 = th[4], th5 = th[5];

    float fx = th0 * xn + th1 * yn + th2;
    float fy = th3 * xn + th4 * yn + th5;

    // source coords: ((f+1)*N - 1)*0.5 ; per +1 output x: dix = th0, diy = th3
    float ixb = (fx + 1.0f) * (0.5f * WW) - 0.5f;
    float iyb = (fy + 1.0f) * (0.5f * HH) - 0.5f;

    unsigned o00[4], o01[4], o10[4], o11[4];
    float    w00[4], w01[4], w10[4], w11[4];
    bool any_valid = false;

#pragma unroll
    for (int k = 0; k < 4; ++k) {
        float ix = ixb + th0 * (float)k;
        float iy = iyb + th3 * (float)k;

        float ix0f = floorf(ix), iy0f = floorf(iy);
        float wx1 = ix - ix0f,  wy1 = iy - iy0f;
        float wx0 = 1.0f - wx1, wy0 = 1.0f - wy1;

        int ix0 = (int)ix0f, iy0 = (int)iy0f;
        int ix1 = ix0 + 1,   iy1 = iy0 + 1;

        bool vx0 = (ix0 >= 0) & (ix0 < WW);
        bool vx1 = (ix1 >= 0) & (ix1 < WW);
        bool vy0 = (iy0 >= 0) & (iy0 < HH);
        bool vy1 = (iy1 >= 0) & (iy1 < HH);

        w00[k] = (vx0 && vy0) ? (wy0 * wx0) : 0.0f;
        w01[k] = (vx1 && vy0) ? (wy0 * wx1) : 0.0f;
        w10[k] = (vx0 && vy1) ? (wy1 * wx0) : 0.0f;
        w11[k] = (vx1 && vy1) ? (wy1 * wx1) : 0.0f;
        any_valid |= (vx0 | vx1) & (vy0 | vy1);

        int cx0 = min(max(ix0, 0), WW - 1), cx1 = min(max(ix1, 0), WW - 1);
        int cy0 = min(max(iy0, 0), HH - 1), cy1 = min(max(iy1, 0), HH - 1);

        o00[k] = (unsigned)cy0 * WW + (unsigned)cx0;
        o01[k] = (unsigned)cy0 * WW + (unsigned)cx1;
        o10[k] = (unsigned)cy1 * WW + (unsigned)cx0;
        o11[k] = (unsigned)cy1 * WW + (unsigned)cx1;
    }

    unsigned obase = b * (unsigned)(CN * OPIX) + yo * OS_ + qx * 4;

    if (!any_valid) {
        vfloat4 z = (vfloat4)(0.0f);
#pragma unroll
        for (int c = 0; c < CN; ++c)
            __builtin_nontemporal_store(z, (vfloat4*)(out + obase + (unsigned)c * OPIX));
        return;
    }

    const float* img = rmap + (size_t)b * (CN * HH * WW);

#pragma unroll 4
    for (int c = 0; c < CN; ++c) {
        const float* ic = img + (size_t)c * (HH * WW);
        vfloat4 v;
        v.x = w00[0]*ic[o00[0]] + w01[0]*ic[o01[0]] + w10[0]*ic[o10[0]] + w11[0]*ic[o11[0]];
        v.y = w00[1]*ic[o00[1]] + w01[1]*ic[o01[1]] + w10[1]*ic[o10[1]] + w11[1]*ic[o11[1]];
        v.z = w00[2]*ic[o00[2]] + w01[2]*ic[o01[2]] + w10[2]*ic[o10[2]] + w11[2]*ic[o11[2]];
        v.w = w00[3]*ic[o00[3]] + w01[3]*ic[o01[3]] + w10[3]*ic[o10[3]] + w11[3]*ic[o11[3]];
        __builtin_nontemporal_store(v, (vfloat4*)(out + obase + (unsigned)c * OPIX));
    }
}

extern "C" void kernel_launch(void* const* d_in, const int* in_sizes, int n_in,
                              void* d_out, int out_size, void* d_ws, size_t ws_size,
                              hipStream_t stream)
{
    const float* ty   = (const float*)d_in[0];
    const float* rmap = (const float*)d_in[1];
    const float* W0   = (const float*)d_in[2];
    const float* b0   = (const float*)d_in[3];
    const float* W1   = (const float*)d_in[4];
    const float* b1   = (const float*)d_in[5];

    float* out       = (float*)d_out;
    float* theta_out = out + (size_t)BN * CN * OPIX;  // theta after samp
    float* theta_ws  = (float*)d_ws;

    theta_kernel<<<1, 128, 0, stream>>>(ty, W0, b0, W1, b1, theta_ws, theta_out);

    int blocks = (NQUAD + 255) / 256;
    sample_kernel<<<blocks, 256, 0, stream>>>(rmap, theta_ws, out);
}

// Round 6
// 365.974 us; speedup vs baseline: 1.0586x; 1.0586x over previous
//
#include <hip/hip_runtime.h>
#include <hip/hip_bf16.h>

#define BN   16
#define CN   16
#define HH   512
#define WW   512
#define CIN_ 10
#define HID_ 64
#define Y0_  100
#define X0_  100
#define OS_  300            // cropped output spatial size
#define OPIX (OS_ * OS_)    // 90000 pixels per (b,c) plane
#define QX_  (OS_ / 4)      // 75 quads per row
#define CPG_ 4              // channels per thread
#define CG_  (CN / CPG_)    // 4 channel groups
#define NTH  (BN * OS_ * QX_ * CG_)   // 1,440,000 threads

typedef float vfloat4 __attribute__((ext_vector_type(4)));

// ---------------------------------------------------------------------------
// Kernel 1: tiny MLP -> theta (fp32 in / fp32 out).
// ---------------------------------------------------------------------------
__global__ void theta_kernel(const float* __restrict__ ty,
                             const float* __restrict__ W0,
                             const float* __restrict__ b0,
                             const float* __restrict__ W1,
                             const float* __restrict__ b1,
                             float* __restrict__ theta_ws,
                             float* __restrict__ theta_out)
{
    int t = threadIdx.x;
    if (t >= BN * 6) return;
    int b = t / 6;
    int j = t - b * 6;

    float tyv[CIN_];
#pragma unroll
    for (int k = 0; k < CIN_; ++k) tyv[k] = ty[b * CIN_ + k];

    float acc = b1[j];
#pragma unroll 4
    for (int i = 0; i < HID_; ++i) {
        float h = b0[i];
#pragma unroll
        for (int k = 0; k < CIN_; ++k) h += tyv[k] * W0[i * CIN_ + k];
        acc += h * W1[j * HID_ + i];
    }

    float v;
    if      (j == 0) v = 1.0f + 0.1f * acc;
    else if (j == 1) v = 0.1f * acc;
    else if (j == 2) v = acc;
    else if (j == 3) v = 0.1f * acc;
    else if (j == 4) v = 1.0f + 0.1f * acc;
    else             v = acc;

    theta_ws[t]  = v;
    theta_out[t] = v;
}

// ---------------------------------------------------------------------------
// Kernel 2: fused affine-grid + bilinear grid-sample + crop.
// Thread = (channel-group of 4, b, yo, qx). qx is the fastest index so a wave
// walks contiguous output (coalesced 16B stores) and near-contiguous source.
// Quad trick: per +1 output x, ix += th0, iy += th3 (affine), so one base
// evaluation + FMAs covers 4 pixels. Per-thread: 64 gathers, 4 NT stores.
// Zero-padding via per-tap weight zeroing; all-OOB fast path.
// ---------------------------------------------------------------------------
__global__ __launch_bounds__(256) void sample_kernel(
    const float* __restrict__ rmap,
    const float* __restrict__ theta,
    float* __restrict__ out)
{
    unsigned gid = blockIdx.x * 256u + threadIdx.x;
    if (gid >= (unsigned)NTH) return;

    unsigned qx = gid % QX_;
    unsigned t1 = gid / QX_;
    unsigned yo = t1 % OS_;
    unsigned t2 = t1 / OS_;
    unsigned b  = t2 % BN;
    unsigned cg = t2 / BN;           // 0..3
    unsigned c0 = cg * CPG_;         // first channel of this thread's group

    int x = (int)(qx * 4) + X0_;     // first pixel of the quad
    int y = (int)yo + Y0_;

    // normalized pixel-center coords: (2*p+1)/N - 1
    float xn = (float)(2 * x + 1) * (1.0f / WW) - 1.0f;
    float yn = (float)(2 * y + 1) * (1.0f / HH) - 1.0f;

    const float* th = theta + b * 6;
    float th0 = th[0], th1 = th[1], th2 = th[2];
    float th3 = th[3], th4 = th[4], th5 = th[5];

    float fx = th0 * xn + th1 * yn + th2;
    float fy = th3 * xn + th4 * yn + th5;

    // source coords: ((f+1)*N - 1)*0.5 ; per +1 output x: dix = th0, diy = th3
    float ixb = (fx + 1.0f) * (0.5f * WW) - 0.5f;
    float iyb = (fy + 1.0f) * (0.5f * HH) - 0.5f;

    unsigned o00[4], o01[4], o10[4], o11[4];
    float    w00[4], w01[4], w10[4], w11[4];
    bool any_valid = false;

#pragma unroll
    for (int k = 0; k < 4; ++k) {
        float ix = ixb + th0 * (float)k;
        float iy = iyb + th3 * (float)k;

        float ix0f = floorf(ix), iy0f = floorf(iy);
        float wx1 = ix - ix0f,  wy1 = iy - iy0f;
        float wx0 = 1.0f - wx1, wy0 = 1.0f - wy1;

        int ix0 = (int)ix0f, iy0 = (int)iy0f;
        int ix1 = ix0 + 1,   iy1 = iy0 + 1;

        bool vx0 = (ix0 >= 0) & (ix0 < WW);
        bool vx1 = (ix1 >= 0) & (ix1 < WW);
        bool vy0 = (iy0 >= 0) & (iy0 < HH);
        bool vy1 = (iy1 >= 0) & (iy1 < HH);

        w00[k] = (vx0 && vy0) ? (wy0 * wx0) : 0.0f;
        w01[k] = (vx1 && vy0) ? (wy0 * wx1) : 0.0f;
        w10[k] = (vx0 && vy1) ? (wy1 * wx0) : 0.0f;
        w11[k] = (vx1 && vy1) ? (wy1 * wx1) : 0.0f;
        any_valid |= (vx0 | vx1) & (vy0 | vy1);

        int cx0 = min(max(ix0, 0), WW - 1), cx1 = min(max(ix1, 0), WW - 1);
        int cy0 = min(max(iy0, 0), HH - 1), cy1 = min(max(iy1, 0), HH - 1);

        o00[k] = (unsigned)cy0 * WW + (unsigned)cx0;
        o01[k] = (unsigned)cy0 * WW + (unsigned)cx1;
        o10[k] = (unsigned)cy1 * WW + (unsigned)cx0;
        o11[k] = (unsigned)cy1 * WW + (unsigned)cx1;
    }

    unsigned obase = (b * (unsigned)CN + c0) * (unsigned)OPIX + yo * OS_ + qx * 4;

    if (!any_valid) {
        vfloat4 z = (vfloat4)(0.0f);
#pragma unroll
        for (int c = 0; c < CPG_; ++c)
            __builtin_nontemporal_store(z, (vfloat4*)(out + obase + (unsigned)c * OPIX));
        return;
    }

    const float* img = rmap + ((size_t)b * CN + c0) * (HH * WW);

#pragma unroll
    for (int c = 0; c < CPG_; ++c) {
        const float* ic = img + (size_t)c * (HH * WW);
        vfloat4 v;
        v.x = w00[0]*ic[o00[0]] + w01[0]*ic[o01[0]] + w10[0]*ic[o10[0]] + w11[0]*ic[o11[0]];
        v.y = w00[1]*ic[o00[1]] + w01[1]*ic[o01[1]] + w10[1]*ic[o10[1]] + w11[1]*ic[o11[1]];
        v.z = w00[2]*ic[o00[2]] + w01[2]*ic[o01[2]] + w10[2]*ic[o10[2]] + w11[2]*ic[o11[2]];
        v.w = w00[3]*ic[o00[3]] + w01[3]*ic[o01[3]] + w10[3]*ic[o10[3]] + w11[3]*ic[o11[3]];
        __builtin_nontemporal_store(v, (vfloat4*)(out + obase + (unsigned)c * OPIX));
    }
}

extern "C" void kernel_launch(void* const* d_in, const int* in_sizes, int n_in,
                              void* d_out, int out_size, void* d_ws, size_t ws_size,
                              hipStream_t stream)
{
    const float* ty   = (const float*)d_in[0];
    const float* rmap = (const float*)d_in[1];
    const float* W0   = (const float*)d_in[2];
    const float* b0   = (const float*)d_in[3];
    const float* W1   = (const float*)d_in[4];
    const float* b1   = (const float*)d_in[5];

    float* out       = (float*)d_out;
    float* theta_out = out + (size_t)BN * CN * OPIX;  // theta after samp
    float* theta_ws  = (float*)d_ws;

    theta_kernel<<<1, 128, 0, stream>>>(ty, W0, b0, W1, b1, theta_ws, theta_out);

    int blocks = (NTH + 255) / 256;
    sample_kernel<<<blocks, 256, 0, stream>>>(rmap, theta_ws, out);
}